// Round 3
// baseline (174.900 us; speedup 1.0000x reference)
//
#include <hip/hip_runtime.h>

// B=4, C=12, D=32, H=128, W=128. S = D*H*W = 524288 voxels per b.
// One pass: softmax over C, accumulate 32 scalars per b, finalize 4 losses.
// R1: 59us main kernel, latency-bound (2 waves/SIMD). R2: grid 1024, acc 53->32.
// R3/R4: float2 staging + TRANS cuts -> only -2us. Spill theory FALSIFIED.
// R5 theory: two stall mechanisms, not pipe limits:
//  (a) convoy: unroll-1 loop = [13 loads, drain, compute]; all waves in
//      lockstep wait ~900cyc HBM latency together. Fix: ping-pong A/B
//      register prefetch -- next tile's loads always in flight.
//  (b) atomic tail: 1024 co-resident blocks finish together, then 32768
//      atomicAdds onto 128 words = 256-deep serial chains. Fix: non-atomic
//      per-block partial stores + parallel-sum finalize; drops zero_acc too.
// PROC numerics bit-identical to R4 (isolate the scheduling variables).

#define S2 262144           // S/2 float2 groups per (b,c) plane
#define BLOCKS_PER_B 256
#define THREADS 256
#define ITERS 4             // 4 float2 groups (8 voxels) per thread
#define NVOX 524288.0f
#define SMOOTH 1e-5f

#define WRED(v) { v += __shfl_down(v,32); v += __shfl_down(v,16); \
                  v += __shfl_down(v,8);  v += __shfl_down(v,4);  \
                  v += __shfl_down(v,2);  v += __shfl_down(v,1); }

// Per-voxel processing; COMP in {x,y}. Numerics identical to R4.
// id1 = t<=4 ? 2t+1 : t+5 ; id2 = t<=3 ? 2t+2 : -1
#define PROC2(X, TG, COMP) do {                                                \
  float xv[12];                                                                \
  _Pragma("unroll")                                                            \
  for (int c = 0; c < 12; ++c) xv[c] = X[c].COMP;                              \
  const int tgt = TG.COMP;                                                     \
  float m = xv[0];                                                             \
  _Pragma("unroll")                                                            \
  for (int c = 1; c < 12; ++c) m = fmaxf(m, xv[c]);                            \
  float e[12]; float es = 0.f;                                                 \
  _Pragma("unroll")                                                            \
  for (int c = 0; c < 12; ++c) { e[c] = __expf(xv[c] - m); es += e[c]; }       \
  const float r = __builtin_amdgcn_rcpf(es);                                   \
  float p[12];                                                                 \
  _Pragma("unroll")                                                            \
  for (int c = 0; c < 12; ++c) {                                               \
    p[c] = e[c] * r;                                                           \
    aZ[c] += p[c] * p[c];                                                      \
    aP[c] += p[c];                                                             \
  }                                                                            \
  float q = 1.f;                                                               \
  _Pragma("unroll")                                                            \
  for (int c = 1; c < 12; ++c) q = __builtin_fmaf(p[c], q, q);                 \
  const float g0 = p[0];                                                       \
  float g1 = 0.f, g2 = 0.f;                                                    \
  _Pragma("unroll")                                                            \
  for (int c = 1; c < 12; ++c) {                                               \
    if (c==1||c==3||c==5||c==7||c==9||c==10||c==11) g1 = (id1==c) ? p[c] : g1; \
    else                                            g2 = (id2==c) ? p[c] : g2; \
  }                                                                            \
  const bool t0 = (tgt == 0);                                                  \
  const bool t1 = (tgt == id1);                                                \
  const bool t2 = (tgt == id2);                                                \
  c0 += t0 ? 1.f : 0.f;  c1 += t1 ? 1.f : 0.f;  c2 += t2 ? 1.f : 0.f;          \
  p0S += t0 ? g0 : 0.f;  p1S += t1 ? g1 : 0.f;  p2S += t2 ? g2 : 0.f;          \
  const float pt = t1 ? g1 : (t2 ? g2 : 0.f);                                  \
  cesE += __logf(q * __builtin_amdgcn_rcpf(1.f + pt));                         \
  float s3 = __expf(g0) + __expf(g1);                                          \
  if (v2) s3 += __expf(g2);                                                    \
  const float gt = t0 ? g0 : (t1 ? g1 : g2);                                   \
  ces += __logf(s3) - gt;                                                      \
} while (0)

#define PROCPAIR(X, T) { PROC2(X, T, x); PROC2(X, T, y); }

#define LOADP(X, T, IT) do {                                                   \
  const int s_ = sBase + (IT) * THREADS;                                       \
  _Pragma("unroll")                                                            \
  for (int c = 0; c < 12; ++c) X[c] = inB[c * S2 + s_];                        \
  T = tgB[s_];                                                                 \
} while (0)

// Slot layout per block (stride 32):
//  0: ces   1: cesE   2,3,4: cnt0,cnt1,cnt2   5,6,7: pTgt0,pTgt1,pTgt2
//  8..19: z[c] = sum p_c^2    20..31: pSum[c] = sum p_c
__global__ __launch_bounds__(THREADS, 4)
void marg_main(const float2* __restrict__ inp, const int2* __restrict__ tgtp,
               const int* __restrict__ task_id, float* __restrict__ acc) {
  const int b   = blockIdx.x / BLOCKS_PER_B;
  const int blk = blockIdx.x % BLOCKS_PER_B;
  const int t   = task_id[b];
  const int id1 = (t <= 4) ? 2*t + 1 : t + 5;
  const int id2 = (t <= 3) ? 2*t + 2 : -1;
  const bool v2 = (id2 >= 0);

  const float2* inB = inp  + (size_t)b * 12 * S2;
  const int2*   tgB = tgtp + (size_t)b * S2;
  const int sBase = blk * (ITERS * THREADS) + (int)threadIdx.x;

  float aZ[12], aP[12];
  #pragma unroll
  for (int c = 0; c < 12; ++c) { aZ[c]=0.f; aP[c]=0.f; }
  float ces=0.f, cesE=0.f, c0=0.f, c1=0.f, c2=0.f, p0S=0.f, p1S=0.f, p2S=0.f;

  // Ping-pong pipeline: next tile's 13 loads in flight under current compute.
  float2 xA[12], xB[12]; int2 tA, tB;
  LOADP(xA, tA, 0);
  LOADP(xB, tB, 1);
  PROCPAIR(xA, tA); LOADP(xA, tA, 2);
  PROCPAIR(xB, tB); LOADP(xB, tB, 3);
  PROCPAIR(xA, tA);
  PROCPAIR(xB, tB);

  WRED(ces); WRED(cesE); WRED(c0); WRED(c1); WRED(c2);
  WRED(p0S); WRED(p1S); WRED(p2S);
  #pragma unroll
  for (int c = 0; c < 12; ++c) { WRED(aZ[c]); WRED(aP[c]); }

  __shared__ float red[4][32];
  const int lane = threadIdx.x & 63;
  const int wv   = threadIdx.x >> 6;
  if (lane == 0) {
    float* rw = red[wv];
    rw[0]=ces; rw[1]=cesE; rw[2]=c0; rw[3]=c1; rw[4]=c2;
    rw[5]=p0S; rw[6]=p1S; rw[7]=p2S;
    #pragma unroll
    for (int c = 0; c < 12; ++c) { rw[8+c]=aZ[c]; rw[20+c]=aP[c]; }
  }
  __syncthreads();
  if (threadIdx.x < 32) {
    const float sv = red[0][threadIdx.x] + red[1][threadIdx.x]
                   + red[2][threadIdx.x] + red[3][threadIdx.x];
    // non-atomic per-block partials; no zeroing needed (fully overwritten)
    acc[(size_t)blockIdx.x * 32 + threadIdx.x] = sv;
  }
}

__global__ void finalize(const float* __restrict__ acc,
                         const int* __restrict__ task_id,
                         float* __restrict__ out) {
  __shared__ float sm[4][32];
  const int tid = threadIdx.x;
  if (tid < 128) {
    const int b = tid >> 5, k = tid & 31;
    const float* base = acc + (size_t)(b * BLOCKS_PER_B) * 32 + k;
    float s0=0.f, s1=0.f, s2=0.f, s3=0.f;
    #pragma unroll 4
    for (int blk = 0; blk < BLOCKS_PER_B; blk += 4) {
      s0 += base[(size_t)(blk+0) * 32];
      s1 += base[(size_t)(blk+1) * 32];
      s2 += base[(size_t)(blk+2) * 32];
      s3 += base[(size_t)(blk+3) * 32];
    }
    sm[b][k] = (s0 + s1) + (s2 + s3);
  }
  __syncthreads();
  if (tid != 0) return;
  float lmd = 0.f, lmce = 0.f, led = 0.f, lece = 0.f;
  for (int b = 0; b < 4; ++b) {
    const float* a = sm[b];
    const int t   = task_id[b];
    const int id1 = (t <= 4) ? 2*t + 1 : t + 5;
    const int id2 = (t <= 3) ? 2*t + 2 : -1;

    lmce += a[0] / NVOX;
    lece += a[1] / NVOX;

    const float d0 = (2.f*a[5] + SMOOTH) / (a[8 + 0]   + a[2] + SMOOTH);
    const float d1 = (2.f*a[6] + SMOOTH) / (a[8 + id1] + a[3] + SMOOTH);
    float d2 = 1.f;
    if (id2 >= 0)
      d2 = (2.f*a[7] + SMOOTH) / (a[8 + id2] + a[4] + SMOOTH);
    lmd += (1.f - d0) + (1.f - d1) + (1.f - d2);

    led += SMOOTH / (a[8] + SMOOTH);
    for (int c = 1; c < 12; ++c) {
      const float ptc  = (c == id1) ? a[6] : ((c == id2) ? a[7] : 0.f);
      const float cntc = (c == id1) ? a[3] : ((c == id2) ? a[4] : 0.f);
      const float inter = a[20 + c] - ptc;
      const float ye    = NVOX - cntc;
      led += (2.f*inter + SMOOTH) / (a[8 + c] + ye + SMOOTH);
    }
  }
  out[0] = lmd  * 0.25f;
  out[1] = lmce * 0.25f;
  out[2] = led  * 0.25f;
  out[3] = lece * 0.25f;
}

extern "C" void kernel_launch(void* const* d_in, const int* in_sizes, int n_in,
                              void* d_out, int out_size, void* d_ws, size_t ws_size,
                              hipStream_t stream) {
  const float* inputs  = (const float*)d_in[0];
  const int*   targets = (const int*)d_in[1];
  const int*   task_id = (const int*)d_in[2];
  float* out = (float*)d_out;
  float* acc = (float*)d_ws;

  marg_main<<<dim3(4 * BLOCKS_PER_B), THREADS, 0, stream>>>(
      (const float2*)inputs, (const int2*)targets, task_id, acc);
  finalize<<<1, 256, 0, stream>>>(acc, task_id, out);
}